// Round 7
// baseline (188.232 us; speedup 1.0000x reference)
//
#include <hip/hip_runtime.h>
#include <math.h>

#define BB 32
#define NN 8192
#define WW 256
#define RR 4
#define CDIM (3*WW + RR + 3)   // 775
#define EPSF 1e-8f

#define K_SEL 128
#define CAP   256

typedef float floatx4 __attribute__((ext_vector_type(4)));

// ---- workspace layout (float offsets) ----
#define O_S      0                      // B*N : p = exp(beta*cossim)
#define O_PHI    (O_S     + BB*NN)      // B*N
#define O_ALLOC  (O_PHI   + BB*NN)      // B*N
#define O_PSUM   (O_ALLOC + BB*NN)      // B*32 partial softmax sums

__device__ __forceinline__ float sigmoidf_(float x) { return 1.0f / (1.0f + expf(-x)); }

// ------- kernel 1: role-split. blocks 0..31: phi/usc/topk/alloc.
//                   blocks 32..1055: dots -> p, per-chunk partial sums. -------
__global__ __launch_bounds__(1024) void mid_kernel(const float* __restrict__ mem,
                                                   const float* __restrict__ controls,
                                                   const float* __restrict__ rw,
                                                   const float* __restrict__ us,
                                                   const float* __restrict__ pw,
                                                   float* __restrict__ ws) {
    __shared__ unsigned hist[4096];            // 16 KB (topk role)
    __shared__ unsigned long long cand[CAP];   //  2 KB
    __shared__ unsigned uscan0[1024];          //  4 KB
    __shared__ unsigned uscan1[1024];          //  4 KB
    __shared__ float    dred[64];              // dots role
    __shared__ int selbin;
    __shared__ unsigned ccnt;

    int t = threadIdx.x;

    if (blockIdx.x < BB) {
        // ================= TOP-K role (one block per batch) =================
        int b = blockIdx.x;
        const float* c = controls + (size_t)b * CDIM;
        float fg[RR];
#pragma unroll
        for (int r = 0; r < RR; r++) fg[r] = sigmoidf_(c[3*WW + r]);

        for (int i = t; i < 4096; i += 1024) hist[i] = 0;
        if (t == 0) { selbin = 0x7FFFFFFF; ccnt = 0; }
        __syncthreads();

        unsigned fb[8];
#pragma unroll
        for (int q = 0; q < 8; q++) {
            int n = t + q * 1024;
            size_t gid = (size_t)b * NN + n;
            float phi = 1.0f;
#pragma unroll
            for (int r = 0; r < RR; r++)
                phi *= (1.0f - fg[r] * rw[((size_t)(b*RR + r)) * NN + n]);
            float u0 = us[gid];
            float u = (u0 + pw[gid] * (1.0f - u0)) * phi;
            float usc = u * (1.0f - EPSF) + EPSF;   // strictly positive, <= 1
            ws[O_PHI   + gid] = phi;
            ws[O_ALLOC + gid] = 0.0f;               // scatter fills top-K below
            fb[q] = __float_as_uint(usc);           // bits monotone for +floats
            atomicAdd(&hist[fb[q] >> 19], 1u);
        }
        __syncthreads();

        // cumulative over 4096 bins (4 bins/thread + 1024-scan)
        unsigned h0 = hist[4*t], h1 = hist[4*t+1], h2 = hist[4*t+2], h3 = hist[4*t+3];
        unsigned tot = h0 + h1 + h2 + h3;
        unsigned *a0 = uscan0, *a1 = uscan1;
        a0[t] = tot;
        __syncthreads();
        for (int off = 1; off < 1024; off <<= 1) {
            unsigned v = a0[t];
            if (t >= off) v += a0[t - off];
            a1[t] = v;
            __syncthreads();
            unsigned* tmp = a0; a0 = a1; a1 = tmp;
        }
        unsigned excl = (t == 0) ? 0u : a0[t - 1];
        {
            unsigned cc = excl;
            unsigned hh[4] = {h0, h1, h2, h3};
#pragma unroll
            for (int j = 0; j < 4; j++) {
                cc += hh[j];
                if (cc >= K_SEL) { atomicMin(&selbin, 4*t + j); break; }
            }
        }
        __syncthreads();
        int Bsel = selbin;

#pragma unroll
        for (int q = 0; q < 8; q++) {
            if ((int)(fb[q] >> 19) <= Bsel) {
                unsigned pos = atomicAdd(&ccnt, 1u);
                if (pos < CAP)
                    cand[pos] = (((unsigned long long)fb[q]) << 32) | (unsigned)(t + q*1024);
            }
        }
        __syncthreads();
        unsigned cnt = min(ccnt, (unsigned)CAP);
        if (t >= cnt && t < CAP) cand[t] = 0x3F800000FFFFFFFFull;  // (1.0f, ~0)
        __syncthreads();

        // bitonic sort CAP keys ascending on (value_bits, idx) -> stable
        for (int k = 2; k <= CAP; k <<= 1) {
            for (int j = k >> 1; j > 0; j >>= 1) {
                if (t < CAP) {
                    int l = t ^ j;
                    if (l > t) {
                        unsigned long long x = cand[t], y = cand[l];
                        bool asc = ((t & k) == 0);
                        if ((x > y) == asc) { cand[t] = y; cand[l] = x; }
                    }
                }
                __syncthreads();
            }
        }

        // exclusive cumprod of sorted values (first CAP threads)
        float v = 1.0f;
        if (t < CAP) v = __uint_as_float((unsigned)(cand[t] >> 32));
        float *f0 = (float*)uscan0, *f1 = (float*)uscan1;
        if (t < CAP) f0[t] = v;
        __syncthreads();
        for (int off = 1; off < CAP; off <<= 1) {
            float x = 0.0f;
            if (t < CAP) { x = f0[t]; if (t >= off) x *= f0[t - off]; }
            __syncthreads();
            if (t < CAP) f1[t] = x;
            __syncthreads();
            float* tmp = f0; f0 = f1; f1 = tmp;
        }
        if (t < CAP) {
            float pre = (t == 0) ? 1.0f : f0[t - 1];
            unsigned idx = (unsigned)(cand[t] & 0xFFFFFFFFull);
            if (idx < NN)
                ws[O_ALLOC + (size_t)b * NN + idx] = (1.0f - v) * pre;
        }
    } else {
        // ================= DOTS role (256 rows per block) =================
        int d = blockIdx.x - BB;
        int b = d >> 5;                 // 32 chunks per batch
        int rowbase = (d & 31) << 8;    // *256
        int wave = t >> 6, lane = t & 63;
        int g  = lane >> 4;             // 4 rows per wave per iter
        int li = lane & 15;             // 16 lanes per row

        const float* c = controls + (size_t)b * CDIM;
        // key fragment: lane li holds floats [li*4 + k*64 .. +3], k=0..3
        float4 k4[4];
        float ksq = 0.0f;
#pragma unroll
        for (int k = 0; k < 4; k++) {
            k4[k].x = c[li*4 + k*64 + 0];
            k4[k].y = c[li*4 + k*64 + 1];
            k4[k].z = c[li*4 + k*64 + 2];
            k4[k].w = c[li*4 + k*64 + 3];
            ksq += k4[k].x*k4[k].x + k4[k].y*k4[k].y + k4[k].z*k4[k].z + k4[k].w*k4[k].w;
        }
#pragma unroll
        for (int off = 8; off > 0; off >>= 1) ksq += __shfl_xor(ksq, off, 64);
        float kn = sqrtf(ksq);
        float bx = c[3*WW + RR];
        float beta = 1.0f + fmaxf(bx, 0.0f) + log1pf(expf(-fabsf(bx)));

        float psum = 0.0f;
#pragma unroll
        for (int p = 0; p < 4; p++) {
            int n = rowbase + wave*16 + p*4 + g;
            const float4* mrow = (const float4*)(mem + ((size_t)b * NN + n) * WW);
            float dot = 0.0f, nn2 = 0.0f;
#pragma unroll
            for (int k = 0; k < 4; k++) {
                float4 m = mrow[li + k*16];
                dot += m.x*k4[k].x + m.y*k4[k].y + m.z*k4[k].z + m.w*k4[k].w;
                nn2 += m.x*m.x + m.y*m.y + m.z*m.z + m.w*m.w;
            }
#pragma unroll
            for (int off = 8; off > 0; off >>= 1) {
                dot += __shfl_xor(dot, off, 64);
                nn2 += __shfl_xor(nn2, off, 64);
            }
            if (li == 0) {
                float pv = expf(dot / (kn * sqrtf(nn2) + EPSF) * beta);
                ws[O_S + (size_t)b * NN + n] = pv;
                psum += pv;
            }
        }
        if (li == 0) dred[wave*4 + g] = psum;
        __syncthreads();
        if (t == 0) {
            float s = 0.0f;
#pragma unroll
            for (int i = 0; i < 64; i++) s += dred[i];
            ws[O_PSUM + b*32 + (d & 31)] = s;
        }
    }
}

// ---------------- kernel 2: fused erase/add update (reverse order) ----------------
__global__ __launch_bounds__(256) void update_kernel(const float* __restrict__ mem,
                                                     const float* __restrict__ controls,
                                                     const float* __restrict__ ws,
                                                     float* __restrict__ out) {
    int bid = gridDim.x - 1 - blockIdx.x;     // reverse: reuse L3-resident tail of mem
    int b  = bid >> 7;
    int rb = (bid & 127) << 6;
    int wave = threadIdx.x >> 6, lane = threadIdx.x & 63;

    const float* c = controls + (size_t)b * CDIM;
    float4 e4, a4;
    e4.x = sigmoidf_(c[WW + lane*4 + 0]);
    e4.y = sigmoidf_(c[WW + lane*4 + 1]);
    e4.z = sigmoidf_(c[WW + lane*4 + 2]);
    e4.w = sigmoidf_(c[WW + lane*4 + 3]);
    a4.x = c[2*WW + lane*4 + 0];
    a4.y = c[2*WW + lane*4 + 1];
    a4.z = c[2*WW + lane*4 + 2];
    a4.w = c[2*WW + lane*4 + 3];
    float ag = sigmoidf_(c[3*WW + RR + 1]);
    float wg = sigmoidf_(c[3*WW + RR + 2]);

    float sum = 0.0f;
#pragma unroll
    for (int i = 0; i < 32; i++) sum += ws[O_PSUM + b*32 + i];
    float iden = 1.0f / sum;

#pragma unroll 4
    for (int it = 0; it < 16; ++it) {
        int n = rb + it*4 + wave;
        size_t row = (size_t)b * NN + n;
        float pv  = ws[O_S + row];
        float al  = ws[O_ALLOC + row];
        float phi = ws[O_PHI + row];
        float cw  = pv * iden;
        float wwt = wg * (ag * al + (1.0f - ag) * cw);
        float4 m = ((const float4*)(mem + row * WW))[lane];
        float4 o;
        o.x = m.x * (1.0f - wwt * e4.x) * phi + wwt * a4.x;
        o.y = m.y * (1.0f - wwt * e4.y) * phi + wwt * a4.y;
        o.z = m.z * (1.0f - wwt * e4.z) * phi + wwt * a4.z;
        o.w = m.w * (1.0f - wwt * e4.w) * phi + wwt * a4.w;
        ((float4*)(out + row * WW))[lane] = o;   // A/B: regular store vs R6's NT store
    }
}

extern "C" void kernel_launch(void* const* d_in, const int* in_sizes, int n_in,
                              void* d_out, int out_size, void* d_ws, size_t ws_size,
                              hipStream_t stream) {
    const float* mem      = (const float*)d_in[0];
    const float* controls = (const float*)d_in[1];
    const float* rw       = (const float*)d_in[2];
    const float* us       = (const float*)d_in[3];
    const float* pw       = (const float*)d_in[4];
    float* out = (float*)d_out;
    float* ws  = (float*)d_ws;

    mid_kernel<<<BB + BB * (NN / 256), 1024, 0, stream>>>(mem, controls, rw, us, pw, ws);
    update_kernel<<<BB * (NN / 64), 256, 0, stream>>>(mem, controls, ws, out);
}

// Round 8
// 144.685 us; speedup vs baseline: 1.3010x; 1.3010x over previous
//
#include <hip/hip_runtime.h>
#include <math.h>

#define BB 32
#define NN 8192
#define WW 256
#define RR 4
#define CDIM (3*WW + RR + 3)   // 775
#define EPSF 1e-8f

#define K_SEL 128
#define CAP   256

typedef float floatx4 __attribute__((ext_vector_type(4)));

// ---- workspace layout (float offsets) ----
#define O_S      0                      // B*N : p = exp(beta*cossim)
#define O_PHI    (O_S     + BB*NN)      // B*N
#define O_ALLOC  (O_PHI   + BB*NN)      // B*N
#define O_PSUM   (O_ALLOC + BB*NN)      // B*32 partial softmax sums

__device__ __forceinline__ float sigmoidf_(float x) { return 1.0f / (1.0f + expf(-x)); }

// ------- kernel 1: role-split. blocks 0..31: phi/usc/topk/alloc.
//                   blocks 32..1055: dots -> p, per-chunk partial sums. -------
__global__ __launch_bounds__(1024) void mid_kernel(const float* __restrict__ mem,
                                                   const float* __restrict__ controls,
                                                   const float* __restrict__ rw,
                                                   const float* __restrict__ us,
                                                   const float* __restrict__ pw,
                                                   float* __restrict__ ws) {
    __shared__ unsigned hist[4096];            // 16 KB (topk role)
    __shared__ unsigned long long cand[CAP];   //  2 KB
    __shared__ unsigned uscan0[1024];          //  4 KB
    __shared__ unsigned uscan1[1024];          //  4 KB
    __shared__ float    dred[64];              // dots role
    __shared__ int selbin;
    __shared__ unsigned ccnt;

    int t = threadIdx.x;

    if (blockIdx.x < BB) {
        // ================= TOP-K role (one block per batch) =================
        int b = blockIdx.x;
        const float* c = controls + (size_t)b * CDIM;
        float fg[RR];
#pragma unroll
        for (int r = 0; r < RR; r++) fg[r] = sigmoidf_(c[3*WW + r]);

        for (int i = t; i < 4096; i += 1024) hist[i] = 0;
        if (t == 0) { selbin = 0x7FFFFFFF; ccnt = 0; }
        __syncthreads();

        unsigned fb[8];
#pragma unroll
        for (int q = 0; q < 8; q++) {
            int n = t + q * 1024;
            size_t gid = (size_t)b * NN + n;
            float phi = 1.0f;
#pragma unroll
            for (int r = 0; r < RR; r++)
                phi *= (1.0f - fg[r] * rw[((size_t)(b*RR + r)) * NN + n]);
            float u0 = us[gid];
            float u = (u0 + pw[gid] * (1.0f - u0)) * phi;
            float usc = u * (1.0f - EPSF) + EPSF;   // strictly positive, <= 1
            ws[O_PHI   + gid] = phi;
            ws[O_ALLOC + gid] = 0.0f;               // scatter fills top-K below
            fb[q] = __float_as_uint(usc);           // bits monotone for +floats
            atomicAdd(&hist[fb[q] >> 19], 1u);
        }
        __syncthreads();

        // cumulative over 4096 bins (4 bins/thread + 1024-scan)
        unsigned h0 = hist[4*t], h1 = hist[4*t+1], h2 = hist[4*t+2], h3 = hist[4*t+3];
        unsigned tot = h0 + h1 + h2 + h3;
        unsigned *a0 = uscan0, *a1 = uscan1;
        a0[t] = tot;
        __syncthreads();
        for (int off = 1; off < 1024; off <<= 1) {
            unsigned v = a0[t];
            if (t >= off) v += a0[t - off];
            a1[t] = v;
            __syncthreads();
            unsigned* tmp = a0; a0 = a1; a1 = tmp;
        }
        unsigned excl = (t == 0) ? 0u : a0[t - 1];
        {
            unsigned cc = excl;
            unsigned hh[4] = {h0, h1, h2, h3};
#pragma unroll
            for (int j = 0; j < 4; j++) {
                cc += hh[j];
                if (cc >= K_SEL) { atomicMin(&selbin, 4*t + j); break; }
            }
        }
        __syncthreads();
        int Bsel = selbin;

#pragma unroll
        for (int q = 0; q < 8; q++) {
            if ((int)(fb[q] >> 19) <= Bsel) {
                unsigned pos = atomicAdd(&ccnt, 1u);
                if (pos < CAP)
                    cand[pos] = (((unsigned long long)fb[q]) << 32) | (unsigned)(t + q*1024);
            }
        }
        __syncthreads();
        unsigned cnt = min(ccnt, (unsigned)CAP);
        if (t >= cnt && t < CAP) cand[t] = 0x3F800000FFFFFFFFull;  // (1.0f, ~0)
        __syncthreads();

        // bitonic sort CAP keys ascending on (value_bits, idx) -> stable
        for (int k = 2; k <= CAP; k <<= 1) {
            for (int j = k >> 1; j > 0; j >>= 1) {
                if (t < CAP) {
                    int l = t ^ j;
                    if (l > t) {
                        unsigned long long x = cand[t], y = cand[l];
                        bool asc = ((t & k) == 0);
                        if ((x > y) == asc) { cand[t] = y; cand[l] = x; }
                    }
                }
                __syncthreads();
            }
        }

        // exclusive cumprod of sorted values (first CAP threads)
        float v = 1.0f;
        if (t < CAP) v = __uint_as_float((unsigned)(cand[t] >> 32));
        float *f0 = (float*)uscan0, *f1 = (float*)uscan1;
        if (t < CAP) f0[t] = v;
        __syncthreads();
        for (int off = 1; off < CAP; off <<= 1) {
            float x = 0.0f;
            if (t < CAP) { x = f0[t]; if (t >= off) x *= f0[t - off]; }
            __syncthreads();
            if (t < CAP) f1[t] = x;
            __syncthreads();
            float* tmp = f0; f0 = f1; f1 = tmp;
        }
        if (t < CAP) {
            float pre = (t == 0) ? 1.0f : f0[t - 1];
            unsigned idx = (unsigned)(cand[t] & 0xFFFFFFFFull);
            if (idx < NN)
                ws[O_ALLOC + (size_t)b * NN + idx] = (1.0f - v) * pre;
        }
    } else {
        // ================= DOTS role (256 rows per block) =================
        int d = blockIdx.x - BB;
        int b = d >> 5;                 // 32 chunks per batch
        int rowbase = (d & 31) << 8;    // *256
        int wave = t >> 6, lane = t & 63;
        int g  = lane >> 4;             // 4 rows per wave per iter
        int li = lane & 15;             // 16 lanes per row

        const float* c = controls + (size_t)b * CDIM;
        // key fragment: lane li holds floats [li*4 + k*64 .. +3], k=0..3
        float4 k4[4];
        float ksq = 0.0f;
#pragma unroll
        for (int k = 0; k < 4; k++) {
            k4[k].x = c[li*4 + k*64 + 0];
            k4[k].y = c[li*4 + k*64 + 1];
            k4[k].z = c[li*4 + k*64 + 2];
            k4[k].w = c[li*4 + k*64 + 3];
            ksq += k4[k].x*k4[k].x + k4[k].y*k4[k].y + k4[k].z*k4[k].z + k4[k].w*k4[k].w;
        }
#pragma unroll
        for (int off = 8; off > 0; off >>= 1) ksq += __shfl_xor(ksq, off, 64);
        float kn = sqrtf(ksq);
        float bx = c[3*WW + RR];
        float beta = 1.0f + fmaxf(bx, 0.0f) + log1pf(expf(-fabsf(bx)));

        float psum = 0.0f;
#pragma unroll
        for (int p = 0; p < 4; p++) {
            int n = rowbase + wave*16 + p*4 + g;
            const float4* mrow = (const float4*)(mem + ((size_t)b * NN + n) * WW);
            float dot = 0.0f, nn2 = 0.0f;
#pragma unroll
            for (int k = 0; k < 4; k++) {
                float4 m = mrow[li + k*16];
                dot += m.x*k4[k].x + m.y*k4[k].y + m.z*k4[k].z + m.w*k4[k].w;
                nn2 += m.x*m.x + m.y*m.y + m.z*m.z + m.w*m.w;
            }
#pragma unroll
            for (int off = 8; off > 0; off >>= 1) {
                dot += __shfl_xor(dot, off, 64);
                nn2 += __shfl_xor(nn2, off, 64);
            }
            if (li == 0) {
                float pv = expf(dot / (kn * sqrtf(nn2) + EPSF) * beta);
                ws[O_S + (size_t)b * NN + n] = pv;
                psum += pv;
            }
        }
        if (li == 0) dred[wave*4 + g] = psum;
        __syncthreads();
        if (t == 0) {
            float s = 0.0f;
#pragma unroll
            for (int i = 0; i < 64; i++) s += dred[i];
            ws[O_PSUM + b*32 + (d & 31)] = s;
        }
    }
}

// ---------------- kernel 2: fused erase/add update (reverse order) ----------------
__global__ __launch_bounds__(256) void update_kernel(const float* __restrict__ mem,
                                                     const float* __restrict__ controls,
                                                     const float* __restrict__ ws,
                                                     float* __restrict__ out) {
    int bid = gridDim.x - 1 - blockIdx.x;     // reverse: reuse L3-resident tail of mem
    int b  = bid >> 7;
    int rb = (bid & 127) << 6;
    int wave = threadIdx.x >> 6, lane = threadIdx.x & 63;

    const float* c = controls + (size_t)b * CDIM;
    float4 e4, a4;
    e4.x = sigmoidf_(c[WW + lane*4 + 0]);
    e4.y = sigmoidf_(c[WW + lane*4 + 1]);
    e4.z = sigmoidf_(c[WW + lane*4 + 2]);
    e4.w = sigmoidf_(c[WW + lane*4 + 3]);
    a4.x = c[2*WW + lane*4 + 0];
    a4.y = c[2*WW + lane*4 + 1];
    a4.z = c[2*WW + lane*4 + 2];
    a4.w = c[2*WW + lane*4 + 3];
    float ag = sigmoidf_(c[3*WW + RR + 1]);
    float wg = sigmoidf_(c[3*WW + RR + 2]);

    float sum = 0.0f;
#pragma unroll
    for (int i = 0; i < 32; i++) sum += ws[O_PSUM + b*32 + i];
    float iden = 1.0f / sum;

#pragma unroll 4
    for (int it = 0; it < 16; ++it) {
        int n = rb + it*4 + wave;
        size_t row = (size_t)b * NN + n;
        float pv  = ws[O_S + row];
        float al  = ws[O_ALLOC + row];
        float phi = ws[O_PHI + row];
        float cw  = pv * iden;
        float wwt = wg * (ag * al + (1.0f - ag) * cw);
        floatx4 m = __builtin_nontemporal_load(&((const floatx4*)(mem + row * WW))[lane]);
        floatx4 o;
        o.x = m.x * (1.0f - wwt * e4.x) * phi + wwt * a4.x;
        o.y = m.y * (1.0f - wwt * e4.y) * phi + wwt * a4.y;
        o.z = m.z * (1.0f - wwt * e4.z) * phi + wwt * a4.z;
        o.w = m.w * (1.0f - wwt * e4.w) * phi + wwt * a4.w;
        __builtin_nontemporal_store(o, &((floatx4*)(out + row * WW))[lane]);
    }
}

extern "C" void kernel_launch(void* const* d_in, const int* in_sizes, int n_in,
                              void* d_out, int out_size, void* d_ws, size_t ws_size,
                              hipStream_t stream) {
    const float* mem      = (const float*)d_in[0];
    const float* controls = (const float*)d_in[1];
    const float* rw       = (const float*)d_in[2];
    const float* us       = (const float*)d_in[3];
    const float* pw       = (const float*)d_in[4];
    float* out = (float*)d_out;
    float* ws  = (float*)d_ws;

    mid_kernel<<<BB + BB * (NN / 256), 1024, 0, stream>>>(mem, controls, rw, us, pw, ws);
    update_kernel<<<BB * (NN / 64), 256, 0, stream>>>(mem, controls, ws, out);
}